// Round 6
// baseline (291.371 us; speedup 1.0000x reference)
//
#include <hip/hip_runtime.h>
#include <math.h>

#define NP 125
#define NC 21
#define THRESH 0.3f

// async global->LDS, 16B per lane (gfx950). LDS dest = wave-uniform base + lane*16.
__device__ inline void ald16(const float* g, float* l) {
    __builtin_amdgcn_global_load_lds(
        (const __attribute__((address_space(1))) void*)g,
        (__attribute__((address_space(3))) void*)l, 16, 0, 0);
}

// ---------- A: streaming logsumexp over all (row,prior); pure BW ----------
// block = 256 threads = 256 consecutive priors; stages 256*21 floats (21504 B).
__global__ void __launch_bounds__(256) mbloss_lse(
    const float* __restrict__ scores, const float* __restrict__ target,
    float2* __restrict__ conf2) {

    __shared__ float s[256 * NC];          // 21504 B -> 7 blocks/CU

    const int tid  = threadIdx.x;
    const int base = blockIdx.x * 256;     // first prior index of this block

    // stage 21504 B: 5 full 4KB sweeps + 1 quarter sweep (tid<64)
    const float* g = scores + (size_t)base * NC;
#pragma unroll
    for (int it = 0; it < 5; ++it) {
        const int off = (it * 256 + tid) * 4;
        ald16(g + off, s + off);
    }
    if (tid < 64) {
        const int off = (5 * 256 + tid) * 4;
        ald16(g + off, s + off);
    }

    // overlap: per-thread row/label (tiny cached loads)
    const int idx = base + tid;            // global prior index
    const int row = idx / NP;
    const int lbl = (int)target[(size_t)row * 8 + 7];

    __syncthreads();

    const float* p = s + tid * NC;         // stride 21 (odd) -> free 2-way alias
    float m = p[0];
#pragma unroll
    for (int c = 1; c < NC; ++c) m = fmaxf(m, p[c]);
    float ss = 0.f;
#pragma unroll
    for (int c = 0; c < NC; ++c) ss += __expf(p[c] - m);
    const float lse = m + __logf(ss);

    conf2[idx] = make_float2(lse - p[lbl], lse - p[0]);   // (pos-variant, neg-variant)
}

// ---------- B: per-row match/sort/reduce; wave per row, no LDS ----------
#define BWAVES 2048
__global__ void __launch_bounds__(256) mbloss_row(
    const float* __restrict__ locs, const float* __restrict__ target,
    const float* __restrict__ priors, const float2* __restrict__ conf2,
    float4* __restrict__ partials, int batch) {

    const int tid  = threadIdx.x;
    const int wave = tid >> 6;
    const int lane = tid & 63;
    const int gw   = blockIdx.x * 4 + wave;      // global wave id [0, BWAVES)

    const int  p1 = lane + 64;
    const bool v1 = (p1 < NP);
    const float4* pr4 = (const float4*)priors;
    float4 P0 = pr4[lane];
    float4 P1 = v1 ? pr4[p1] : make_float4(0.f, 0.f, 1.f, 1.f);

    float acc_conf = 0.f, acc_sl1 = 0.f, acc_ang = 0.f, acc_np = 0.f;

    for (int r = gw; r < batch; r += BWAVES) {
        const float* t = target + (size_t)r * 8;
        const float bx = t[0], by = t[1], bw = t[2], bh = t[3];
        const float sa = t[5], ca = t[6];

        float iou0, iou1 = -1.f;
        {
            float iw = fminf(bx + bw * 0.5f, P0.x + P0.z * 0.5f) -
                       fmaxf(bx - bw * 0.5f, P0.x - P0.z * 0.5f);
            float ih = fminf(by + bh * 0.5f, P0.y + P0.w * 0.5f) -
                       fmaxf(by - bh * 0.5f, P0.y - P0.w * 0.5f);
            iw = fmaxf(iw, 0.f); ih = fmaxf(ih, 0.f);
            float inter = iw * ih;
            iou0 = inter / (bw * bh + P0.z * P0.w - inter);
        }
        if (v1) {
            float iw = fminf(bx + bw * 0.5f, P1.x + P1.z * 0.5f) -
                       fmaxf(bx - bw * 0.5f, P1.x - P1.z * 0.5f);
            float ih = fminf(by + bh * 0.5f, P1.y + P1.w * 0.5f) -
                       fmaxf(by - bh * 0.5f, P1.y - P1.w * 0.5f);
            iw = fmaxf(iw, 0.f); ih = fmaxf(ih, 0.f);
            float inter = iw * ih;
            iou1 = inter / (bw * bh + P1.z * P1.w - inter);
        }

        // coalesced conf loads (issue early; independent of argmax)
        float2 c0 = conf2[(size_t)r * NP + lane];
        float2 c1 = v1 ? conf2[(size_t)r * NP + p1] : make_float2(0.f, -1.f);

        // argmax, first-index tie-break, butterfly (all lanes agree)
        float bv = iou0; int bi = lane;
        if (iou1 > bv) { bv = iou1; bi = p1; }
#pragma unroll
        for (int off = 1; off < 64; off <<= 1) {
            float vo = __shfl_xor(bv, off, 64);
            int   io = __shfl_xor(bi, off, 64);
            if (vo > bv || (vo == bv && io < bi)) { bv = vo; bi = io; }
        }
        const int best = bi;

        const bool pos0 = (lane == best) || (iou0 >= THRESH);
        const bool pos1 = v1 && ((p1 == best) || (iou1 >= THRESH));
        const int npos = __popcll(__ballot(pos0)) + __popcll(__ballot(pos1));
        acc_np += (pos0 ? 1.f : 0.f) + (pos1 ? 1.f : 0.f);

#define SL1(d) (fabsf(d) < 1.f ? 0.5f * (d) * (d) : fabsf(d) - 0.5f)
        if (pos0) {
            acc_conf += c0.x;
            const float* L = locs + (size_t)r * (NP * 6) + lane * 6;
            float g0 = (bx - P0.x) / (P0.z * 0.1f);
            float g1 = (by - P0.y) / (P0.w * 0.1f);
            float g2 = __logf(bw / P0.z) * 5.f;
            float g3 = __logf(bh / P0.w) * 5.f;
            float d0 = L[0] - g0, d1 = L[1] - g1, d2 = L[2] - g2, d3 = L[3] - g3;
            acc_sl1 += SL1(d0) + SL1(d1) + SL1(d2) + SL1(d3);
            float a0 = L[4] - sa, a1 = L[5] - ca;
            acc_ang += a0 * a0 + a1 * a1;
        }
        if (pos1) {
            acc_conf += c1.x;
            const float* L = locs + (size_t)r * (NP * 6) + p1 * 6;
            float g0 = (bx - P1.x) / (P1.z * 0.1f);
            float g1 = (by - P1.y) / (P1.w * 0.1f);
            float g2 = __logf(bw / P1.z) * 5.f;
            float g3 = __logf(bh / P1.w) * 5.f;
            float d0 = L[0] - g0, d1 = L[1] - g1, d2 = L[2] - g2, d3 = L[3] - g3;
            acc_sl1 += SL1(d0) + SL1(d1) + SL1(d2) + SL1(d3);
            float a0 = L[4] - sa, a1 = L[5] - ca;
            acc_ang += a0 * a0 + a1 * a1;
        }

        // register bitonic sort of conf_neg (128 virtual elems, descending)
        float x0 = pos0 ? 0.f : c0.y;                  // conf_neg >= 0 always
        float x1 = v1 ? (pos1 ? 0.f : c1.y) : -1.f;    // pads sort last
#pragma unroll
        for (int k = 2; k <= 128; k <<= 1) {
#pragma unroll
            for (int j = k >> 1; j >= 1; j >>= 1) {
                if (j == 64) {
                    float a = fmaxf(x0, x1), b = fminf(x0, x1);
                    x0 = a; x1 = b;
                } else {
                    bool lower = (lane & j) == 0;
                    bool d0 = ((lane & k) == 0);
                    bool d1 = (((lane + 64) & k) == 0);
                    float o0 = __shfl_xor(x0, j, 64);
                    float o1 = __shfl_xor(x1, j, 64);
                    x0 = (lower == d0) ? fmaxf(x0, o0) : fminf(x0, o0);
                    x1 = (lower == d1) ? fmaxf(x1, o1) : fminf(x1, o1);
                }
            }
        }

        int kk = 3 * npos; if (kk > NP) kk = NP;
        acc_conf += (lane < kk ? x0 : 0.f) + (lane + 64 < kk ? x1 : 0.f);
    }

    // wave reduce, one float4 store per wave
#pragma unroll
    for (int off = 1; off < 64; off <<= 1) {
        acc_conf += __shfl_xor(acc_conf, off, 64);
        acc_sl1  += __shfl_xor(acc_sl1,  off, 64);
        acc_ang  += __shfl_xor(acc_ang,  off, 64);
        acc_np   += __shfl_xor(acc_np,   off, 64);
    }
    if (lane == 0) partials[gw] = make_float4(acc_conf, acc_sl1, acc_ang, acc_np);
}

// ---------- fin: reduce 2048 partials ----------
__global__ void __launch_bounds__(1024) mbloss_fin(const float4* __restrict__ partials,
                                                   int n, float* __restrict__ out) {
    __shared__ float4 red[1024];
    const int tid = threadIdx.x;
    float4 a = make_float4(0.f, 0.f, 0.f, 0.f);
    for (int i = tid; i < n; i += 1024) {
        float4 p = partials[i];
        a.x += p.x; a.y += p.y; a.z += p.z; a.w += p.w;
    }
    red[tid] = a;
    __syncthreads();
    for (int s = 512; s > 0; s >>= 1) {
        if (tid < s) {
            red[tid].x += red[tid + s].x; red[tid].y += red[tid + s].y;
            red[tid].z += red[tid + s].z; red[tid].w += red[tid + s].w;
        }
        __syncthreads();
    }
    if (tid == 0) {
        float npt  = red[0].w;
        float conf = red[0].x / npt;
        float loc  = red[0].y / (npt * 4.f);
        float ang  = 25.f * red[0].z / (npt * 2.f);
        out[0] = conf; out[1] = loc; out[2] = ang; out[3] = conf + loc + ang;
    }
}

extern "C" void kernel_launch(void* const* d_in, const int* in_sizes, int n_in,
                              void* d_out, int out_size, void* d_ws, size_t ws_size,
                              hipStream_t stream) {
    const float* locs   = (const float*)d_in[0];
    const float* scores = (const float*)d_in[1];
    const float* target = (const float*)d_in[2];
    const float* priors = (const float*)d_in[3];
    float* out = (float*)d_out;

    const int batch = in_sizes[2] / 8;        // target is (B,1,8); 16384
    const int npri  = batch * NP;             // 2,048,000 (divisible by 256)

    float2* conf2    = (float2*)d_ws;                              // 16 MB
    float4* partials = (float4*)((char*)d_ws + (size_t)npri * 8);  // 32 KB

    mbloss_lse<<<npri / 256, 256, 0, stream>>>(scores, target, conf2);
    mbloss_row<<<BWAVES / 4, 256, 0, stream>>>(locs, target, priors, conf2,
                                               partials, batch);
    mbloss_fin<<<1, 1024, 0, stream>>>(partials, BWAVES, out);
}

// Round 7
// 290.544 us; speedup vs baseline: 1.0028x; 1.0028x over previous
//
#include <hip/hip_runtime.h>
#include <math.h>

#define NP 125
#define NC 21
#define THRESH 0.3f

// ---------- A: streaming logsumexp; thread per prior, registers only ----------
__global__ void __launch_bounds__(256) mbloss_lse(
    const float* __restrict__ scores, const float* __restrict__ target,
    float2* __restrict__ conf2, int npri) {

    const int idx = blockIdx.x * 256 + threadIdx.x;   // global prior index
    if (idx >= npri) return;
    const int row = idx / NP;
    const int lbl = (int)target[(size_t)row * 8 + 7];

    const float* p = scores + (size_t)idx * NC;
    float v[NC];
#pragma unroll
    for (int c = 0; c < NC; ++c) v[c] = p[c];         // 21 outstanding loads

    float m = v[0];
#pragma unroll
    for (int c = 1; c < NC; ++c) m = fmaxf(m, v[c]);
    float ss = 0.f, picked = 0.f;
#pragma unroll
    for (int c = 0; c < NC; ++c) {
        ss += __expf(v[c] - m);
        picked += (c == lbl) ? v[c] : 0.f;            // cndmask, no reg-indexing
    }
    const float lse = m + __logf(ss);

    conf2[idx] = make_float2(lse - picked, lse - v[0]);  // (pos-variant, neg-variant)
}

// ---------- B: per-row match/sort/reduce; wave per row, no LDS ----------
#define BWAVES 2048
__global__ void __launch_bounds__(256) mbloss_row(
    const float* __restrict__ locs, const float* __restrict__ target,
    const float* __restrict__ priors, const float2* __restrict__ conf2,
    float4* __restrict__ partials, int batch) {

    const int tid  = threadIdx.x;
    const int wave = tid >> 6;
    const int lane = tid & 63;
    const int gw   = blockIdx.x * 4 + wave;      // global wave id [0, BWAVES)

    const int  p1 = lane + 64;
    const bool v1 = (p1 < NP);
    const float4* pr4 = (const float4*)priors;
    float4 P0 = pr4[lane];
    float4 P1 = v1 ? pr4[p1] : make_float4(0.f, 0.f, 1.f, 1.f);

    float acc_conf = 0.f, acc_sl1 = 0.f, acc_ang = 0.f, acc_np = 0.f;

    for (int r = gw; r < batch; r += BWAVES) {
        const float* t = target + (size_t)r * 8;
        const float bx = t[0], by = t[1], bw = t[2], bh = t[3];
        const float sa = t[5], ca = t[6];

        float iou0, iou1 = -1.f;
        {
            float iw = fminf(bx + bw * 0.5f, P0.x + P0.z * 0.5f) -
                       fmaxf(bx - bw * 0.5f, P0.x - P0.z * 0.5f);
            float ih = fminf(by + bh * 0.5f, P0.y + P0.w * 0.5f) -
                       fmaxf(by - bh * 0.5f, P0.y - P0.w * 0.5f);
            iw = fmaxf(iw, 0.f); ih = fmaxf(ih, 0.f);
            float inter = iw * ih;
            iou0 = inter / (bw * bh + P0.z * P0.w - inter);
        }
        if (v1) {
            float iw = fminf(bx + bw * 0.5f, P1.x + P1.z * 0.5f) -
                       fmaxf(bx - bw * 0.5f, P1.x - P1.z * 0.5f);
            float ih = fminf(by + bh * 0.5f, P1.y + P1.w * 0.5f) -
                       fmaxf(by - bh * 0.5f, P1.y - P1.w * 0.5f);
            iw = fmaxf(iw, 0.f); ih = fmaxf(ih, 0.f);
            float inter = iw * ih;
            iou1 = inter / (bw * bh + P1.z * P1.w - inter);
        }

        // coalesced conf loads (issue early; independent of argmax)
        float2 c0 = conf2[(size_t)r * NP + lane];
        float2 c1 = v1 ? conf2[(size_t)r * NP + p1] : make_float2(0.f, -1.f);

        // argmax, first-index tie-break, butterfly (all lanes agree)
        float bv = iou0; int bi = lane;
        if (iou1 > bv) { bv = iou1; bi = p1; }
#pragma unroll
        for (int off = 1; off < 64; off <<= 1) {
            float vo = __shfl_xor(bv, off, 64);
            int   io = __shfl_xor(bi, off, 64);
            if (vo > bv || (vo == bv && io < bi)) { bv = vo; bi = io; }
        }
        const int best = bi;

        const bool pos0 = (lane == best) || (iou0 >= THRESH);
        const bool pos1 = v1 && ((p1 == best) || (iou1 >= THRESH));
        const int npos = __popcll(__ballot(pos0)) + __popcll(__ballot(pos1));
        acc_np += (pos0 ? 1.f : 0.f) + (pos1 ? 1.f : 0.f);

#define SL1(d) (fabsf(d) < 1.f ? 0.5f * (d) * (d) : fabsf(d) - 0.5f)
        if (pos0) {
            acc_conf += c0.x;
            const float* L = locs + (size_t)r * (NP * 6) + lane * 6;
            float g0 = (bx - P0.x) / (P0.z * 0.1f);
            float g1 = (by - P0.y) / (P0.w * 0.1f);
            float g2 = __logf(bw / P0.z) * 5.f;
            float g3 = __logf(bh / P0.w) * 5.f;
            float d0 = L[0] - g0, d1 = L[1] - g1, d2 = L[2] - g2, d3 = L[3] - g3;
            acc_sl1 += SL1(d0) + SL1(d1) + SL1(d2) + SL1(d3);
            float a0 = L[4] - sa, a1 = L[5] - ca;
            acc_ang += a0 * a0 + a1 * a1;
        }
        if (pos1) {
            acc_conf += c1.x;
            const float* L = locs + (size_t)r * (NP * 6) + p1 * 6;
            float g0 = (bx - P1.x) / (P1.z * 0.1f);
            float g1 = (by - P1.y) / (P1.w * 0.1f);
            float g2 = __logf(bw / P1.z) * 5.f;
            float g3 = __logf(bh / P1.w) * 5.f;
            float d0 = L[0] - g0, d1 = L[1] - g1, d2 = L[2] - g2, d3 = L[3] - g3;
            acc_sl1 += SL1(d0) + SL1(d1) + SL1(d2) + SL1(d3);
            float a0 = L[4] - sa, a1 = L[5] - ca;
            acc_ang += a0 * a0 + a1 * a1;
        }

        // register bitonic sort of conf_neg (128 virtual elems, descending)
        float x0 = pos0 ? 0.f : c0.y;                  // conf_neg >= 0 always
        float x1 = v1 ? (pos1 ? 0.f : c1.y) : -1.f;    // pads sort last
#pragma unroll
        for (int k = 2; k <= 128; k <<= 1) {
#pragma unroll
            for (int j = k >> 1; j >= 1; j >>= 1) {
                if (j == 64) {
                    float a = fmaxf(x0, x1), b = fminf(x0, x1);
                    x0 = a; x1 = b;
                } else {
                    bool lower = (lane & j) == 0;
                    bool d0 = ((lane & k) == 0);
                    bool d1 = (((lane + 64) & k) == 0);
                    float o0 = __shfl_xor(x0, j, 64);
                    float o1 = __shfl_xor(x1, j, 64);
                    x0 = (lower == d0) ? fmaxf(x0, o0) : fminf(x0, o0);
                    x1 = (lower == d1) ? fmaxf(x1, o1) : fminf(x1, o1);
                }
            }
        }

        int kk = 3 * npos; if (kk > NP) kk = NP;
        acc_conf += (lane < kk ? x0 : 0.f) + (lane + 64 < kk ? x1 : 0.f);
    }

    // wave reduce, one float4 store per wave
#pragma unroll
    for (int off = 1; off < 64; off <<= 1) {
        acc_conf += __shfl_xor(acc_conf, off, 64);
        acc_sl1  += __shfl_xor(acc_sl1,  off, 64);
        acc_ang  += __shfl_xor(acc_ang,  off, 64);
        acc_np   += __shfl_xor(acc_np,   off, 64);
    }
    if (lane == 0) partials[gw] = make_float4(acc_conf, acc_sl1, acc_ang, acc_np);
}

// ---------- fin: reduce 2048 partials ----------
__global__ void __launch_bounds__(1024) mbloss_fin(const float4* __restrict__ partials,
                                                   int n, float* __restrict__ out) {
    __shared__ float4 red[1024];
    const int tid = threadIdx.x;
    float4 a = make_float4(0.f, 0.f, 0.f, 0.f);
    for (int i = tid; i < n; i += 1024) {
        float4 p = partials[i];
        a.x += p.x; a.y += p.y; a.z += p.z; a.w += p.w;
    }
    red[tid] = a;
    __syncthreads();
    for (int s = 512; s > 0; s >>= 1) {
        if (tid < s) {
            red[tid].x += red[tid + s].x; red[tid].y += red[tid + s].y;
            red[tid].z += red[tid + s].z; red[tid].w += red[tid + s].w;
        }
        __syncthreads();
    }
    if (tid == 0) {
        float npt  = red[0].w;
        float conf = red[0].x / npt;
        float loc  = red[0].y / (npt * 4.f);
        float ang  = 25.f * red[0].z / (npt * 2.f);
        out[0] = conf; out[1] = loc; out[2] = ang; out[3] = conf + loc + ang;
    }
}

extern "C" void kernel_launch(void* const* d_in, const int* in_sizes, int n_in,
                              void* d_out, int out_size, void* d_ws, size_t ws_size,
                              hipStream_t stream) {
    const float* locs   = (const float*)d_in[0];
    const float* scores = (const float*)d_in[1];
    const float* target = (const float*)d_in[2];
    const float* priors = (const float*)d_in[3];
    float* out = (float*)d_out;

    const int batch = in_sizes[2] / 8;        // target is (B,1,8); 16384
    const int npri  = batch * NP;             // 2,048,000

    float2* conf2    = (float2*)d_ws;                              // 16 MB
    float4* partials = (float4*)((char*)d_ws + (size_t)npri * 8);  // 32 KB

    mbloss_lse<<<(npri + 255) / 256, 256, 0, stream>>>(scores, target, conf2, npri);
    mbloss_row<<<BWAVES / 4, 256, 0, stream>>>(locs, target, priors, conf2,
                                               partials, batch);
    mbloss_fin<<<1, 1024, 0, stream>>>(partials, BWAVES, out);
}

// Round 8
// 271.027 us; speedup vs baseline: 1.0751x; 1.0720x over previous
//
#include <hip/hip_runtime.h>
#include <math.h>

#define NP 125
#define NC 21
#define ROWF (NP * NC)        // 2625 floats = 10500 B per score row
#define THRESH 0.3f

// async global->LDS (gfx950). LDS dest layout = wave-uniform base + lane*size.
__device__ inline void ald16(const float* g, float* l) {
    __builtin_amdgcn_global_load_lds(
        (const __attribute__((address_space(1))) void*)g,
        (__attribute__((address_space(3))) void*)l, 16, 0, 0);
}
__device__ inline void ald4(const float* g, float* l) {
    __builtin_amdgcn_global_load_lds(
        (const __attribute__((address_space(1))) void*)g,
        (__attribute__((address_space(3))) void*)l, 4, 0, 0);
}

// vmcnt-only waits: expcnt=7 (no wait), lgkmcnt=0xF (no wait on 4-bit CDNA enc)
#define WAIT_VM5()  do { __builtin_amdgcn_s_waitcnt(0xF75); __builtin_amdgcn_sched_barrier(0); } while (0)
#define WAIT_VM0()  do { __builtin_amdgcn_s_waitcnt(0xF70); __builtin_amdgcn_sched_barrier(0); } while (0)

// one 64-thread block (one wave) per batch row; no s_barrier anywhere.
__global__ void __launch_bounds__(64) mbloss_main(
    const float* __restrict__ locs, const float* __restrict__ scores,
    const float* __restrict__ target, const float* __restrict__ priors,
    float4* __restrict__ partials) {

    __shared__ float s_sc[ROWF];           // 10.5 KB -> ~15 blocks/CU

    const int lane = threadIdx.x;
    const int r    = blockIdx.x;

    // ---- uniform target via scalar path (lgkm counter, not vmcnt) ----
    const float* t = target + (size_t)r * 8;
    const float bx = t[0], by = t[1], bw = t[2], bh = t[3];
    const float sa = t[5], ca = t[6];
    const int lblT = (int)t[7];

    // ---- priors (vmem, issued BEFORE the DMAs) ----
    const int  p1 = lane + 64;
    const bool v1 = (p1 < NP);
    const float4* pr4 = (const float4*)priors;
    float4 P0 = pr4[lane];
    float4 P1 = v1 ? pr4[p1] : make_float4(0.f, 0.f, 1.f, 1.f);

    // ---- issue 11 async LDS-DMAs (newest vmem ops; sweeps of 1024 B/lane-grp) ----
    const float* gsc = scores + (size_t)r * ROWF;
#pragma unroll
    for (int it = 0; it < 10; ++it) {               // floats [0, 2560)
        const int off = it * 256 + lane * 4;
        ald16(gsc + off, s_sc + off);
    }
    ald4(gsc + 2560 + lane, s_sc + 2560 + lane);    // floats [2560, 2624)
    if (lane == 0) s_sc[2624] = gsc[2624];          // last float (vmem + ds_write)

    // ---- IoU + argmax + pos (overlaps DMA flight; waits only on priors) ----
    float iou0, iou1 = -1.f;
    {
        float iw = fminf(bx + bw * 0.5f, P0.x + P0.z * 0.5f) -
                   fmaxf(bx - bw * 0.5f, P0.x - P0.z * 0.5f);
        float ih = fminf(by + bh * 0.5f, P0.y + P0.w * 0.5f) -
                   fmaxf(by - bh * 0.5f, P0.y - P0.w * 0.5f);
        iw = fmaxf(iw, 0.f); ih = fmaxf(ih, 0.f);
        float inter = iw * ih;
        iou0 = inter / (bw * bh + P0.z * P0.w - inter);
    }
    if (v1) {
        float iw = fminf(bx + bw * 0.5f, P1.x + P1.z * 0.5f) -
                   fmaxf(bx - bw * 0.5f, P1.x - P1.z * 0.5f);
        float ih = fminf(by + bh * 0.5f, P1.y + P1.w * 0.5f) -
                   fmaxf(by - bh * 0.5f, P1.y - P1.w * 0.5f);
        iw = fmaxf(iw, 0.f); ih = fmaxf(ih, 0.f);
        float inter = iw * ih;
        iou1 = inter / (bw * bh + P1.z * P1.w - inter);
    }

    float bv = iou0; int bi = lane;
    if (iou1 > bv) { bv = iou1; bi = p1; }
#pragma unroll
    for (int off = 1; off < 64; off <<= 1) {
        float vo = __shfl_xor(bv, off, 64);
        int   io = __shfl_xor(bi, off, 64);
        if (vo > bv || (vo == bv && io < bi)) { bv = vo; bi = io; }
    }
    const int best = bi;

    const bool pos0 = (lane == best) || (iou0 >= THRESH);
    const bool pos1 = v1 && ((p1 == best) || (iou1 >= THRESH));
    const int npos = __popcll(__ballot(pos0)) + __popcll(__ballot(pos1));
    const float acc_np = (pos0 ? 1.f : 0.f) + (pos1 ? 1.f : 0.f);
    float acc_conf = 0.f, acc_sl1 = 0.f, acc_ang = 0.f;

    // issue predicated locs loads now (in flight across the LSE compute)
    float L0a = 0.f, L0b = 0.f, L0c = 0.f, L0d = 0.f, L0e = 0.f, L0f = 0.f;
    float L1a = 0.f, L1b = 0.f, L1c = 0.f, L1d = 0.f, L1e = 0.f, L1f = 0.f;
    if (pos0) {
        const float* L = locs + (size_t)r * (NP * 6) + lane * 6;
        L0a = L[0]; L0b = L[1]; L0c = L[2]; L0d = L[3]; L0e = L[4]; L0f = L[5];
    }
    if (pos1) {
        const float* L = locs + (size_t)r * (NP * 6) + p1 * 6;
        L1a = L[0]; L1b = L[1]; L1c = L[2]; L1d = L[3]; L1e = L[4]; L1f = L[5];
    }

    // ---- phase 1: first 6 DMAs done -> p0's scores (floats < 1344) ----
    WAIT_VM5();
    float conf0;
    {
        const float* s0 = s_sc + lane * NC;
        float m = s0[0];
#pragma unroll
        for (int c = 1; c < NC; ++c) m = fmaxf(m, s0[c]);
        float ss = 0.f;
#pragma unroll
        for (int c = 0; c < NC; ++c) ss += __expf(s0[c] - m);
        conf0 = (m + __logf(ss)) - s0[pos0 ? lblT : 0];
    }

    // ---- phase 2: all DMAs done -> p1's scores ----
    WAIT_VM0();
    float conf1 = 0.f;
    if (v1) {
        const float* s1 = s_sc + p1 * NC;
        float m = s1[0];
#pragma unroll
        for (int c = 1; c < NC; ++c) m = fmaxf(m, s1[c]);
        float ss = 0.f;
#pragma unroll
        for (int c = 0; c < NC; ++c) ss += __expf(s1[c] - m);
        conf1 = (m + __logf(ss)) - s1[pos1 ? lblT : 0];
    }
    if (pos0) acc_conf += conf0;
    if (pos1) acc_conf += conf1;

    // ---- positive-prior loc/angle losses (locs already landed) ----
#define SL1(d) (fabsf(d) < 1.f ? 0.5f * (d) * (d) : fabsf(d) - 0.5f)
    if (pos0) {
        float g0 = (bx - P0.x) / (P0.z * 0.1f);
        float g1 = (by - P0.y) / (P0.w * 0.1f);
        float g2 = __logf(bw / P0.z) * 5.f;
        float g3 = __logf(bh / P0.w) * 5.f;
        float d0 = L0a - g0, d1 = L0b - g1, d2 = L0c - g2, d3 = L0d - g3;
        acc_sl1 += SL1(d0) + SL1(d1) + SL1(d2) + SL1(d3);
        float a0 = L0e - sa, a1 = L0f - ca;
        acc_ang += a0 * a0 + a1 * a1;
    }
    if (pos1) {
        float g0 = (bx - P1.x) / (P1.z * 0.1f);
        float g1 = (by - P1.y) / (P1.w * 0.1f);
        float g2 = __logf(bw / P1.z) * 5.f;
        float g3 = __logf(bh / P1.w) * 5.f;
        float d0 = L1a - g0, d1 = L1b - g1, d2 = L1c - g2, d3 = L1d - g3;
        acc_sl1 += SL1(d0) + SL1(d1) + SL1(d2) + SL1(d3);
        float a0 = L1e - sa, a1 = L1f - ca;
        acc_ang += a0 * a0 + a1 * a1;
    }

    // ---- register bitonic sort of conf_neg (128 virtual elems, descending) ----
    float x0 = pos0 ? 0.f : conf0;                 // conf_neg >= 0 always
    float x1 = v1 ? (pos1 ? 0.f : conf1) : -1.f;   // pads sort last
#pragma unroll
    for (int k = 2; k <= 128; k <<= 1) {
#pragma unroll
        for (int j = k >> 1; j >= 1; j >>= 1) {
            if (j == 64) {
                float a = fmaxf(x0, x1), b = fminf(x0, x1);
                x0 = a; x1 = b;
            } else {
                bool lower = (lane & j) == 0;
                bool d0 = ((lane & k) == 0);
                bool d1 = (((lane + 64) & k) == 0);
                float o0 = __shfl_xor(x0, j, 64);
                float o1 = __shfl_xor(x1, j, 64);
                x0 = (lower == d0) ? fmaxf(x0, o0) : fminf(x0, o0);
                x1 = (lower == d1) ? fmaxf(x1, o1) : fminf(x1, o1);
            }
        }
    }

    // ---- hard-negative top-k (k = min(3*npos, 125)) ----
    int kk = 3 * npos; if (kk > NP) kk = NP;
    acc_conf += (lane < kk ? x0 : 0.f) + (lane + 64 < kk ? x1 : 0.f);

    // ---- wave reduce, one float4 store per row ----
    float rc = acc_conf, rs = acc_sl1, ra = acc_ang, rn = acc_np;
#pragma unroll
    for (int off = 1; off < 64; off <<= 1) {
        rc += __shfl_xor(rc, off, 64);
        rs += __shfl_xor(rs, off, 64);
        ra += __shfl_xor(ra, off, 64);
        rn += __shfl_xor(rn, off, 64);
    }
    if (lane == 0) partials[r] = make_float4(rc, rs, ra, rn);
}

__global__ void __launch_bounds__(1024) mbloss_fin(const float4* __restrict__ partials,
                                                   int n, float* __restrict__ out) {
    __shared__ float4 red[1024];
    const int tid = threadIdx.x;
    float4 a = make_float4(0.f, 0.f, 0.f, 0.f);
    for (int i = tid; i < n; i += 1024) {
        float4 p = partials[i];
        a.x += p.x; a.y += p.y; a.z += p.z; a.w += p.w;
    }
    red[tid] = a;
    __syncthreads();
    for (int s = 512; s > 0; s >>= 1) {
        if (tid < s) {
            red[tid].x += red[tid + s].x; red[tid].y += red[tid + s].y;
            red[tid].z += red[tid + s].z; red[tid].w += red[tid + s].w;
        }
        __syncthreads();
    }
    if (tid == 0) {
        float npt  = red[0].w;
        float conf = red[0].x / npt;
        float loc  = red[0].y / (npt * 4.f);
        float ang  = 25.f * red[0].z / (npt * 2.f);
        out[0] = conf; out[1] = loc; out[2] = ang; out[3] = conf + loc + ang;
    }
}

extern "C" void kernel_launch(void* const* d_in, const int* in_sizes, int n_in,
                              void* d_out, int out_size, void* d_ws, size_t ws_size,
                              hipStream_t stream) {
    const float* locs   = (const float*)d_in[0];
    const float* scores = (const float*)d_in[1];
    const float* target = (const float*)d_in[2];
    const float* priors = (const float*)d_in[3];
    float* out = (float*)d_out;

    const int batch = in_sizes[2] / 8;   // target is (B,1,8)

    float4* partials = (float4*)d_ws;    // batch * 16 B = 256 KB << ws_size

    mbloss_main<<<batch, 64, 0, stream>>>(locs, scores, target, priors, partials);
    mbloss_fin<<<1, 1024, 0, stream>>>(partials, batch, out);
}